// Round 1
// baseline (1112.035 us; speedup 1.0000x reference)
//
#include <hip/hip_runtime.h>
#include <hip/hip_bf16.h>
#include <stdint.h>

#define NTOK 4096      // B*S
#define DIM  1024      // D
#define FF   4096      // F
#define NE   8         // experts
#define NPAIR (NTOK*2) // top-2

using short8 = __attribute__((ext_vector_type(8))) short;
using f32x4  = __attribute__((ext_vector_type(4))) float;
typedef unsigned short u16;
typedef unsigned int   u32;

__device__ __forceinline__ u16 f2bf(float f) {
  union { float f; u32 u; } v; v.f = f;
  u32 r = (v.u + 0x7fffu + ((v.u >> 16) & 1u)) >> 16;
  return (u16)r;
}
__device__ __forceinline__ u32 pack2(float lo, float hi) {
  return (u32)f2bf(lo) | ((u32)f2bf(hi) << 16);
}
__device__ __forceinline__ float gelu_tanh(float x) {
  // jax.nn.gelu default (approximate=True)
  float z = 0.7978845608028654f * (x + 0.044715f * x * x * x);
  return 0.5f * x * (1.0f + tanhf(z));
}

// ---------------- conversions f32 -> bf16 (relayout per-expert) ----------------
__global__ __launch_bounds__(256) void cvt_x_kernel(const float4* __restrict__ in, uint2* __restrict__ out) {
  int i = blockIdx.x * 256 + threadIdx.x;            // NTOK*DIM/4 elems
  float4 v = in[i];
  out[i] = make_uint2(pack2(v.x, v.y), pack2(v.z, v.w));
}

__global__ __launch_bounds__(256) void cvt_w1_kernel(const float* __restrict__ w1, u16* __restrict__ w1b) {
  // in: [F][E][D]  ->  out: [E][F][D]
  size_t i4 = (size_t)blockIdx.x * 256 + threadIdx.x;  // E*F*D/4
  int d4 = (int)(i4 & (DIM/4 - 1));
  size_t t = i4 >> 8;               // / (DIM/4)
  int f = (int)(t & (FF - 1));
  int e = (int)(t >> 12);
  float4 v = *(const float4*)(w1 + ((size_t)f * NE + e) * DIM + (size_t)d4 * 4);
  *(uint2*)(w1b + ((size_t)e * FF + f) * DIM + (size_t)d4 * 4) =
      make_uint2(pack2(v.x, v.y), pack2(v.z, v.w));
}

__global__ __launch_bounds__(256) void cvt_w2_kernel(const float* __restrict__ w2, u16* __restrict__ w2b) {
  // in: [D][E][F]  ->  out: [E][D][F]
  size_t i4 = (size_t)blockIdx.x * 256 + threadIdx.x;  // E*D*F/4
  int f4 = (int)(i4 & (FF/4 - 1));
  size_t t = i4 >> 10;              // / (FF/4)
  int d = (int)(t & (DIM - 1));
  int e = (int)(t >> 10);
  float4 v = *(const float4*)(w2 + ((size_t)d * NE + e) * FF + (size_t)f4 * 4);
  *(uint2*)(w2b + ((size_t)e * DIM + d) * FF + (size_t)f4 * 4) =
      make_uint2(pack2(v.x, v.y), pack2(v.z, v.w));
}

// ---------------- gating: logits -> softmax -> top2 ----------------
__global__ __launch_bounds__(256) void gate_kernel(const float* __restrict__ x, const float* __restrict__ gw,
                                                   int* __restrict__ tk_e, float* __restrict__ tk_p,
                                                   int* __restrict__ counts) {
  int tok  = blockIdx.x * 4 + (threadIdx.x >> 6);
  int lane = threadIdx.x & 63;
  const float* xr = x + (size_t)tok * DIM;
  float acc[NE];
#pragma unroll
  for (int e = 0; e < NE; ++e) acc[e] = 0.f;
#pragma unroll
  for (int it = 0; it < 4; ++it) {
    int d = it * 256 + lane * 4;
    float4 xv = *(const float4*)(xr + d);
#pragma unroll
    for (int e = 0; e < NE; ++e) {
      float4 gv = *(const float4*)(gw + (size_t)e * DIM + d);
      acc[e] += xv.x * gv.x + xv.y * gv.y + xv.z * gv.z + xv.w * gv.w;
    }
  }
#pragma unroll
  for (int e = 0; e < NE; ++e)
#pragma unroll
    for (int off = 32; off; off >>= 1) acc[e] += __shfl_xor(acc[e], off);

  if (lane == 0) {
    float mx = acc[0];
#pragma unroll
    for (int e = 1; e < NE; ++e) mx = fmaxf(mx, acc[e]);
    float pr[NE]; float s = 0.f;
#pragma unroll
    for (int e = 0; e < NE; ++e) { pr[e] = __expf(acc[e] - mx); s += pr[e]; }
    float inv = 1.f / s;
    int e0 = 0; float p0 = pr[0];
#pragma unroll
    for (int e = 1; e < NE; ++e) if (pr[e] > p0) { p0 = pr[e]; e0 = e; }
    int e1 = (e0 == 0) ? 1 : 0; float p1 = pr[e1];
#pragma unroll
    for (int e = 0; e < NE; ++e) if (e != e0 && pr[e] > p1) { p1 = pr[e]; e1 = e; }
    tk_e[tok * 2]     = e0; tk_p[tok * 2]     = p0 * inv;
    tk_e[tok * 2 + 1] = e1; tk_p[tok * 2 + 1] = p1 * inv;
    atomicAdd(&counts[e0], 1);
    atomicAdd(&counts[e1], 1);
  }
}

__global__ void route_offsets_kernel(const int* __restrict__ counts, int* __restrict__ offsets,
                                     int* __restrict__ cursors) {
  if (threadIdx.x == 0) { int s = 0; for (int e = 0; e < NE; ++e) { offsets[e] = s; s += counts[e]; } }
  if (threadIdx.x < NE) cursors[threadIdx.x] = 0;
}

__global__ __launch_bounds__(256) void scatter_kernel(const int* __restrict__ tk_e, const float* __restrict__ tk_p,
                                                      const int* __restrict__ offsets, int* __restrict__ cursors,
                                                      int* __restrict__ pair_tok, float* __restrict__ pair_p) {
  int i = blockIdx.x * 256 + threadIdx.x;   // NPAIR
  int e = tk_e[i];
  int pos = atomicAdd(&cursors[e], 1);
  int slot = offsets[e] + pos;
  pair_tok[slot] = i >> 1;
  pair_p[slot]   = tk_p[i];
}

// ---------------- grouped GEMM1: h = gelu(x[tok] @ w1_e^T + b1_e) ----------------
__global__ __launch_bounds__(256) void gemm1_kernel(const u16* __restrict__ xb, const u16* __restrict__ w1b,
                                                    const float* __restrict__ b1g,
                                                    const int* __restrict__ pair_tok,
                                                    const int* __restrict__ offsets, const int* __restrict__ counts,
                                                    u16* __restrict__ h) {
  int e = blockIdx.x >> 5;
  int trow = blockIdx.x & 31;
  int M = counts[e];
  if (trow * 128 >= M) return;
  int off = offsets[e];
  int fblk = blockIdx.y * 128;

  __shared__ u16 As[2][128 * 32];
  __shared__ u16 Bs[2][128 * 32];

  int tid = threadIdx.x, lane = tid & 63, wave = tid >> 6;
  int wr = wave >> 1, wc = wave & 1;

  // staging mapping: pass p covers rows [p*64, p*64+64); thread t -> row t/4, colgrp t%4 (8 bf16 each)
  int r0 = tid >> 2, c0 = tid & 3;
  int arow0 = trow * 128 + r0, arow1 = arow0 + 64;
  int t0 = pair_tok[off + (arow0 < M - 1 ? arow0 : M - 1)];
  int t1 = pair_tok[off + (arow1 < M - 1 ? arow1 : M - 1)];
  const u16* a0 = xb + (size_t)t0 * DIM + c0 * 8;
  const u16* a1 = xb + (size_t)t1 * DIM + c0 * 8;
  const u16* b0 = w1b + ((size_t)e * FF + fblk + r0) * DIM + c0 * 8;
  const u16* b1p = w1b + ((size_t)e * FF + fblk + r0 + 64) * DIM + c0 * 8;

  f32x4 acc[4][4];
#pragma unroll
  for (int i = 0; i < 4; ++i)
#pragma unroll
    for (int j = 0; j < 4; ++j)
#pragma unroll
      for (int k = 0; k < 4; ++k) acc[i][j][k] = 0.f;

  uint4 ra0, ra1, rb0, rb1;
  auto LOADK = [&](int kt) {
    int ko = kt * 32;
    ra0 = *(const uint4*)(a0 + ko);
    ra1 = *(const uint4*)(a1 + ko);
    rb0 = *(const uint4*)(b0 + ko);
    rb1 = *(const uint4*)(b1p + ko);
  };
  auto WRITES = [&](int b) {
    *(uint4*)&As[b][r0 * 32 + c0 * 8]        = ra0;
    *(uint4*)&As[b][(r0 + 64) * 32 + c0 * 8] = ra1;
    *(uint4*)&Bs[b][r0 * 32 + c0 * 8]        = rb0;
    *(uint4*)&Bs[b][(r0 + 64) * 32 + c0 * 8] = rb1;
  };
  LOADK(0); WRITES(0);
  const int nk = DIM / 32;
  int frow = lane & 15, kgrp = (lane >> 4) * 8;
  for (int kt = 0; kt < nk; ++kt) {
    __syncthreads();
    if (kt + 1 < nk) LOADK(kt + 1);
    int b = kt & 1;
    short8 af[4], bf[4];
#pragma unroll
    for (int i = 0; i < 4; ++i) {
      af[i] = *(const short8*)&As[b][(wr * 64 + i * 16 + frow) * 32 + kgrp];
      bf[i] = *(const short8*)&Bs[b][(wc * 64 + i * 16 + frow) * 32 + kgrp];
    }
#pragma unroll
    for (int i = 0; i < 4; ++i)
#pragma unroll
      for (int j = 0; j < 4; ++j)
        acc[i][j] = __builtin_amdgcn_mfma_f32_16x16x32_bf16(af[i], bf[j], acc[i][j], 0, 0, 0);
    if (kt + 1 < nk) WRITES((kt + 1) & 1);
  }

  int rq = lane >> 4;
#pragma unroll
  for (int i = 0; i < 4; ++i) {
#pragma unroll
    for (int r = 0; r < 4; ++r) {
      int m = wr * 64 + i * 16 + rq * 4 + r;
      int row = trow * 128 + m;
      if (row < M) {
        size_t hbase = (size_t)(off + row) * FF;
#pragma unroll
        for (int j = 0; j < 4; ++j) {
          int f = fblk + wc * 64 + j * 16 + (lane & 15);
          float v = acc[i][j][r] + b1g[e * FF + f];
          h[hbase + f] = f2bf(gelu_tanh(v));
        }
      }
    }
  }
}

// ---------------- grouped GEMM2: out += p * (h @ w2_e^T + b2_e) ----------------
__global__ __launch_bounds__(256) void gemm2_kernel(const u16* __restrict__ h, const u16* __restrict__ w2b,
                                                    const float* __restrict__ b2g,
                                                    const int* __restrict__ pair_tok, const float* __restrict__ pair_p,
                                                    const int* __restrict__ offsets, const int* __restrict__ counts,
                                                    float* __restrict__ out) {
  int e = blockIdx.x >> 5;
  int trow = blockIdx.x & 31;
  int M = counts[e];
  if (trow * 128 >= M) return;
  int off = offsets[e];
  int dblk = blockIdx.y * 128;

  __shared__ u16 As[2][128 * 32];
  __shared__ u16 Bs[2][128 * 32];

  int tid = threadIdx.x, lane = tid & 63, wave = tid >> 6;
  int wr = wave >> 1, wc = wave & 1;

  int r0 = tid >> 2, c0 = tid & 3;
  int arow0 = trow * 128 + r0, arow1 = arow0 + 64;
  int s0 = off + (arow0 < M - 1 ? arow0 : M - 1);
  int s1 = off + (arow1 < M - 1 ? arow1 : M - 1);
  const u16* a0 = h + (size_t)s0 * FF + c0 * 8;
  const u16* a1 = h + (size_t)s1 * FF + c0 * 8;
  const u16* b0 = w2b + ((size_t)e * DIM + dblk + r0) * FF + c0 * 8;
  const u16* b1p = w2b + ((size_t)e * DIM + dblk + r0 + 64) * FF + c0 * 8;

  f32x4 acc[4][4];
#pragma unroll
  for (int i = 0; i < 4; ++i)
#pragma unroll
    for (int j = 0; j < 4; ++j)
#pragma unroll
      for (int k = 0; k < 4; ++k) acc[i][j][k] = 0.f;

  uint4 ra0, ra1, rb0, rb1;
  auto LOADK = [&](int kt) {
    int ko = kt * 32;
    ra0 = *(const uint4*)(a0 + ko);
    ra1 = *(const uint4*)(a1 + ko);
    rb0 = *(const uint4*)(b0 + ko);
    rb1 = *(const uint4*)(b1p + ko);
  };
  auto WRITES = [&](int b) {
    *(uint4*)&As[b][r0 * 32 + c0 * 8]        = ra0;
    *(uint4*)&As[b][(r0 + 64) * 32 + c0 * 8] = ra1;
    *(uint4*)&Bs[b][r0 * 32 + c0 * 8]        = rb0;
    *(uint4*)&Bs[b][(r0 + 64) * 32 + c0 * 8] = rb1;
  };
  LOADK(0); WRITES(0);
  const int nk = FF / 32;
  int frow = lane & 15, kgrp = (lane >> 4) * 8;
  for (int kt = 0; kt < nk; ++kt) {
    __syncthreads();
    if (kt + 1 < nk) LOADK(kt + 1);
    int b = kt & 1;
    short8 af[4], bf[4];
#pragma unroll
    for (int i = 0; i < 4; ++i) {
      af[i] = *(const short8*)&As[b][(wr * 64 + i * 16 + frow) * 32 + kgrp];
      bf[i] = *(const short8*)&Bs[b][(wc * 64 + i * 16 + frow) * 32 + kgrp];
    }
#pragma unroll
    for (int i = 0; i < 4; ++i)
#pragma unroll
      for (int j = 0; j < 4; ++j)
        acc[i][j] = __builtin_amdgcn_mfma_f32_16x16x32_bf16(af[i], bf[j], acc[i][j], 0, 0, 0);
    if (kt + 1 < nk) WRITES((kt + 1) & 1);
  }

  int rq = lane >> 4;
#pragma unroll
  for (int i = 0; i < 4; ++i) {
#pragma unroll
    for (int r = 0; r < 4; ++r) {
      int m = wr * 64 + i * 16 + rq * 4 + r;
      int row = trow * 128 + m;
      if (row < M) {
        int slot = off + row;
        int tok = pair_tok[slot];
        float p = pair_p[slot];
#pragma unroll
        for (int j = 0; j < 4; ++j) {
          int d = dblk + wc * 64 + j * 16 + (lane & 15);
          float v = (acc[i][j][r] + b2g[e * DIM + d]) * p;
          atomicAdd(&out[(size_t)tok * DIM + d], v);
        }
      }
    }
  }
}

extern "C" void kernel_launch(void* const* d_in, const int* in_sizes, int n_in,
                              void* d_out, int out_size, void* d_ws, size_t ws_size,
                              hipStream_t stream) {
  const float* x  = (const float*)d_in[0];
  const float* gw = (const float*)d_in[1];
  const float* w1 = (const float*)d_in[2];
  const float* b1 = (const float*)d_in[3];
  const float* w2 = (const float*)d_in[4];
  const float* b2 = (const float*)d_in[5];
  float* out = (float*)d_out;

  char* ws = (char*)d_ws;
  size_t o = 0;
  auto alloc = [&](size_t bytes) { void* p = ws + o; o += (bytes + 255) & ~(size_t)255; return p; };
  u16*   xb       = (u16*)alloc((size_t)NTOK * DIM * 2);
  u16*   w1b      = (u16*)alloc((size_t)NE * FF * DIM * 2);
  u16*   w2b      = (u16*)alloc((size_t)NE * DIM * FF * 2);
  u16*   hbuf     = (u16*)alloc((size_t)NPAIR * FF * 2);
  int*   tk_e     = (int*)alloc((size_t)NPAIR * 4);
  float* tk_p     = (float*)alloc((size_t)NPAIR * 4);
  int*   pair_tok = (int*)alloc((size_t)NPAIR * 4);
  float* pair_p   = (float*)alloc((size_t)NPAIR * 4);
  int*   counts   = (int*)alloc(NE * 4);
  int*   offsets  = (int*)alloc(NE * 4);
  int*   cursors  = (int*)alloc(NE * 4);
  if (o > ws_size) return;  // workspace too small: fail loudly rather than corrupt

  hipMemsetAsync(counts, 0, NE * 4, stream);
  hipMemsetAsync(out, 0, (size_t)NTOK * DIM * 4, stream);

  cvt_x_kernel <<<NTOK * DIM / 4 / 256, 256, 0, stream>>>((const float4*)x, (uint2*)xb);
  cvt_w1_kernel<<<NE * FF * DIM / 4 / 256, 256, 0, stream>>>(w1, w1b);
  cvt_w2_kernel<<<NE * DIM * FF / 4 / 256, 256, 0, stream>>>(w2, w2b);
  gate_kernel  <<<NTOK / 4, 256, 0, stream>>>(x, gw, tk_e, tk_p, counts);
  route_offsets_kernel<<<1, 64, 0, stream>>>(counts, offsets, cursors);
  scatter_kernel<<<NPAIR / 256, 256, 0, stream>>>(tk_e, tk_p, offsets, cursors, pair_tok, pair_p);
  gemm1_kernel<<<dim3(NE * 32, FF / 128), 256, 0, stream>>>(xb, w1b, b1, pair_tok, offsets, counts, hbuf);
  gemm2_kernel<<<dim3(NE * 32, DIM / 128), 256, 0, stream>>>(hbuf, w2b, b2, pair_tok, pair_p, offsets, counts, out);
}